// Round 8
// baseline (208.561 us; speedup 1.0000x reference)
//
#include <hip/hip_runtime.h>
#include <hip/hip_bf16.h>
#include <math.h>

constexpr int T_SEQ = 2049;
constexpr int D_MODEL = 1024;
constexpr int N_HEAD = 16;
constexpr int HEAD_DIM = 64;
constexpr int VT_STRIDE = 2112;  // 2048+64: all V tile reads in-bounds, zero-padded
constexpr int T1_ROWS = 1152;    // rows 1024..2175 for split partial buffers

typedef __attribute__((ext_vector_type(8))) short short8;
typedef __attribute__((ext_vector_type(4))) short short4v;
typedef __attribute__((ext_vector_type(4))) float floatx4;

// async global->LDS, 16B per lane; LDS dest = wave-uniform base + lane*16
__device__ inline void load_lds16(const void* g, void* l) {
  __builtin_amdgcn_global_load_lds(
      (const __attribute__((address_space(1))) unsigned int*)g,
      (__attribute__((address_space(3))) unsigned int*)l, 16, 0, 0);
}

__device__ inline short8 cvt8_bf16(const float* p) {
  float4 a = *(const float4*)p, b = *(const float4*)(p + 4);
  __hip_bfloat16 t[8] = {__float2bfloat16(a.x), __float2bfloat16(a.y),
                         __float2bfloat16(a.z), __float2bfloat16(a.w),
                         __float2bfloat16(b.x), __float2bfloat16(b.y),
                         __float2bfloat16(b.z), __float2bfloat16(b.w)};
  return *(const short8*)t;
}

__device__ inline float bf2f(__hip_bfloat16 x) { return __bfloat162float(x); }

// ---------------------------------------------------------------------------
// Mega-cast: all 7 fp32->bf16 tensors in one launch. grid=(1025,7)
// ---------------------------------------------------------------------------
__global__ __launch_bounds__(256) void cast_all(
    const float* __restrict__ q, const float* __restrict__ k,
    const float* __restrict__ v, const float* __restrict__ wq,
    const float* __restrict__ wk, const float* __restrict__ wv,
    const float* __restrict__ wo, __hip_bfloat16* __restrict__ qo,
    __hip_bfloat16* __restrict__ ko, __hip_bfloat16* __restrict__ vo,
    __hip_bfloat16* __restrict__ wqo, __hip_bfloat16* __restrict__ wko,
    __hip_bfloat16* __restrict__ wvo, __hip_bfloat16* __restrict__ woo) {
  const int z = blockIdx.y;
  const float* in;
  __hip_bfloat16* out;
  int n;
  switch (z) {
    case 0: in = q; out = qo; n = T_SEQ * D_MODEL; break;
    case 1: in = k; out = ko; n = T_SEQ * D_MODEL; break;
    case 2: in = v; out = vo; n = T_SEQ * D_MODEL; break;
    case 3: in = wq; out = wqo; n = D_MODEL * D_MODEL; break;
    case 4: in = wk; out = wko; n = D_MODEL * D_MODEL; break;
    case 5: in = wv; out = wvo; n = D_MODEL * D_MODEL; break;
    default: in = wo; out = woo; n = D_MODEL * D_MODEL; break;
  }
  const int i = (blockIdx.x * 256 + threadIdx.x) * 8;
  if (i + 8 > n) return;
  *(short8*)(out + i) = cvt8_bf16(in + i);
}

// ---------------------------------------------------------------------------
// bf16 MFMA GEMM v2: C[M x 1024] = A[M x 1024] @ W[1024 x 1024]^T + bias
// BM=64 x BN tile, BK=64, 256 threads (2x2 waves, wave tile 32 x BN/2).
// DOUBLE-BUFFERED LDS, one barrier per K-iter (flash-style pipeline):
//   prestage(0); loop { sync; stage(j+1,buf^1); compute(buf) }
// Staging: 8 rows x 8 slots/instr; chunk c of row r at slot c^(r&7) (conflict
// -free, proven by round-7 SQ_LDS_BANK_CONFLICT=0).
// OUTK: 0 -> fp32 row-major; 2 -> QKV mode (z<2 bf16 head-major, z==2 bf16 row)
// ---------------------------------------------------------------------------
template <int BN, int OUTK>
__global__ __launch_bounds__(256) void mfma_gemm(
    const __hip_bfloat16* __restrict__ A0, const __hip_bfloat16* __restrict__ A1,
    const __hip_bfloat16* __restrict__ A2, const __hip_bfloat16* __restrict__ W0,
    const __hip_bfloat16* __restrict__ W1, const __hip_bfloat16* __restrict__ W2,
    const float* __restrict__ bias0, const float* __restrict__ bias1,
    const float* __restrict__ bias2, void* C0, void* C1, void* C2, int M) {
  constexpr int K = D_MODEL;
  constexpr int NT = BN / 32;  // B fragment tiles per wave
  __shared__ __align__(16) __hip_bfloat16 As[2][64 * 64];
  __shared__ __align__(16) __hip_bfloat16 Bs[2][BN * 64];

  const int z = blockIdx.z;
  const short* A = (const short*)(z == 0 ? A0 : z == 1 ? A1 : A2);
  const short* W = (const short*)(z == 0 ? W0 : z == 1 ? W1 : W2);
  const float* bias = z == 0 ? bias0 : z == 1 ? bias1 : bias2;
  void* C = z == 0 ? C0 : z == 1 ? C1 : C2;

  const int tid = threadIdx.x;
  const int wave = tid >> 6, lane = tid & 63;
  const int col = lane & 15, quad = lane >> 4;
  const int wm = wave >> 1, wn = wave & 1;
  const int m0 = blockIdx.y * 64, n0 = blockIdx.x * BN;

  // staging lane geometry: 8 rows x 8 slots (16B) per instruction
  const int srow = lane >> 3;    // 0..7
  const int sslot = lane & 7;    // 0..7
  const int sch = sslot ^ srow;  // global chunk fetched into this lane's slot

  floatx4 acc[2][NT];
#pragma unroll
  for (int i = 0; i < 2; i++)
#pragma unroll
    for (int j = 0; j < NT; j++) acc[i][j] = (floatx4){0.f, 0.f, 0.f, 0.f};

#define GSTAGE(K0, BUF)                                                     \
  {                                                                         \
    _Pragma("unroll") for (int ii = 0; ii < 2; ii++) {                      \
      const int rb = (wave * 2 + ii) * 8;                                   \
      const int am = min(m0 + rb + srow, M - 1);                            \
      load_lds16(A + (size_t)am * K + (K0) + sch * 8,                       \
                 (char*)&As[BUF][0] + rb * 128);                            \
    }                                                                       \
    _Pragma("unroll") for (int ii = 0; ii < BN / 32; ii++) {                \
      const int rb = (wave * (BN / 32) + ii) * 8;                           \
      const int bn = n0 + rb + srow;                                        \
      load_lds16(W + (size_t)bn * K + (K0) + sch * 8,                       \
                 (char*)&Bs[BUF][0] + rb * 128);                            \
    }                                                                       \
  }

  GSTAGE(0, 0)
  int buf = 0;

  for (int kb = 0; kb < K / 64; ++kb, buf ^= 1) {
    __syncthreads();  // drain stage(kb); all waves done reading buf^1
    if (kb + 1 < K / 64) GSTAGE((kb + 1) * 64, buf ^ 1)

    const __hip_bfloat16* as = &As[buf][0];
    const __hip_bfloat16* bs = &Bs[buf][0];
#pragma unroll
    for (int kk = 0; kk < 2; kk++) {
      short8 af[2], bf[NT];
#pragma unroll
      for (int t = 0; t < 2; t++) {
        const int ra = wm * 32 + t * 16 + col;
        af[t] = *(const short8*)(as + ra * 64 + ((kk * 4 + quad) ^ (ra & 7)) * 8);
      }
#pragma unroll
      for (int t = 0; t < NT; t++) {
        const int rb = wn * (BN / 2) + t * 16 + col;
        bf[t] = *(const short8*)(bs + rb * 64 + ((kk * 4 + quad) ^ (rb & 7)) * 8);
      }
#pragma unroll
      for (int mt = 0; mt < 2; mt++)
#pragma unroll
        for (int nt = 0; nt < NT; nt++)
          acc[mt][nt] = __builtin_amdgcn_mfma_f32_16x16x32_bf16(af[mt], bf[nt],
                                                                acc[mt][nt], 0, 0, 0);
    }
  }

#pragma unroll
  for (int mt = 0; mt < 2; mt++) {
#pragma unroll
    for (int r = 0; r < 4; r++) {
      const int m = m0 + wm * 32 + mt * 16 + quad * 4 + r;
      if (m >= M) continue;
#pragma unroll
      for (int nt = 0; nt < NT; nt++) {
        const int n = n0 + wn * (BN / 2) + nt * 16 + col;
        const float val = acc[mt][nt][r] + bias[n];
        if (OUTK == 0) {
          ((float*)C)[(size_t)m * D_MODEL + n] = val;
        } else {
          if (z < 2) {  // head-major [h][t][hd] for Q,K
            const int h = n >> 6, hd = n & 63;
            ((__hip_bfloat16*)C)[((size_t)h * T_SEQ + m) * HEAD_DIM + hd] =
                __float2bfloat16(val);
          } else {  // row-major for V (transpose kernel reads this)
            ((__hip_bfloat16*)C)[(size_t)m * D_MODEL + n] = __float2bfloat16(val);
          }
        }
      }
    }
  }
}

// ---------------------------------------------------------------------------
// Transpose V per head (+ fold in Er fp32->bf16 cast on the extra y-slice).
// grid = (65, 17): y<16,x<33 -> transpose tile; y==16 -> Er cast (65 blocks)
// ---------------------------------------------------------------------------
__global__ __launch_bounds__(256) void transpose_v_er(
    const __hip_bfloat16* __restrict__ vpr, __hip_bfloat16* __restrict__ vt,
    const float* __restrict__ Er, __hip_bfloat16* __restrict__ er_bf) {
  const int tid = threadIdx.x;
  if (blockIdx.y == 16) {
    const int i = (blockIdx.x * 256 + tid) * 8;
    if (i + 8 <= T_SEQ * HEAD_DIM) *(short8*)(er_bf + i) = cvt8_bf16(Er + i);
    return;
  }
  if (blockIdx.x >= 33) return;

  __shared__ __align__(16) __hip_bfloat16 tile[64][72];
  const int t0 = blockIdx.x * 64;
  const int h = blockIdx.y;
  const short* plane = (const short*)vpr;
  short* oplane = (short*)(vt + (size_t)h * HEAD_DIM * VT_STRIDE);

  for (int idx = tid; idx < 64 * 8; idx += 256) {
    const int row = idx >> 3, ch = idx & 7;
    const int t = t0 + row;
    short8 v = {0, 0, 0, 0, 0, 0, 0, 0};
    if (t < T_SEQ) v = *(const short8*)(plane + (size_t)t * D_MODEL + h * 64 + ch * 8);
    *(short8*)&tile[row][ch * 8] = v;
  }
  __syncthreads();
  for (int idx = tid; idx < 64 * 8; idx += 256) {
    const int d = idx >> 3, ch = idx & 7;
    short8 v;
#pragma unroll
    for (int i = 0; i < 8; i++) v[i] = *(const short*)&tile[ch * 8 + i][d];
    *(short8*)(oplane + (size_t)d * VT_STRIDE + t0 + ch * 8) = v;
  }
}

// ---------------------------------------------------------------------------
// Flash attention v3: S^T trick + no-max softmax (logits bounded ~|4.5| ->
// exp <= ~90, fp32-safe) -> order-free s-tiles -> split-s load balancing.
// b<8: qt=b, full s-range, COMPLETE sum -> write normalized ctx directly.
// b>=8: qt=8+((b-8)>>1), s-half (b-8)&1 -> partial (O,l) buffers (t>=1024).
// ---------------------------------------------------------------------------
__global__ __launch_bounds__(512, 4) void flash_attn(
    const __hip_bfloat16* __restrict__ qh, const __hip_bfloat16* __restrict__ kh,
    const __hip_bfloat16* __restrict__ er, const __hip_bfloat16* __restrict__ vt,
    __hip_bfloat16* __restrict__ ctx, __hip_bfloat16* __restrict__ O0,
    __hip_bfloat16* __restrict__ O1, float* __restrict__ l0g,
    float* __restrict__ l1g) {
  __shared__ __align__(16) __hip_bfloat16 Ks[2][64 * 128];  // [s][kaug] swizzled
  __shared__ __align__(16) __hip_bfloat16 Vs[2][64 * 64];   // [d][s] swizzled
  __shared__ __align__(16) __hip_bfloat16 Ps[8][1024];      // per-wave frag-major

  const int tid = threadIdx.x;
  const int h = blockIdx.y;
  const int b = blockIdx.x;  // 0..25

  const int qt = (b < 8) ? b : 8 + ((b - 8) >> 1);
  const int tq0 = qt * 128;
  const int jmax = min(tq0 + 127, T_SEQ - 1) >> 6;
  int j0, j1;
  bool alt;
  if (b < 8) {
    j0 = 0; j1 = jmax; alt = false;
  } else {
    const int mid = (jmax + 1) >> 1;
    alt = (b - 8) & 1;
    j0 = alt ? mid : 0;
    j1 = alt ? jmax : mid - 1;
  }

  const int wave = tid >> 6;
  const int lane = tid & 63;
  const int col = lane & 15;
  const int quad = lane >> 4;

  const short* qplane = (const short*)(qh + (size_t)h * T_SEQ * HEAD_DIM);
  const short* kplane = (const short*)(kh + (size_t)h * T_SEQ * HEAD_DIM);
  const short* eplane = (const short*)er;
  const short* vplane = (const short*)(vt + (size_t)h * HEAD_DIM * VT_STRIDE);

  // ---- Q fragments (B-operand): lane holds Qaug[t = tq0+wave*16+col][k]
  const int t_abs = tq0 + wave * 16 + col;
  const int tload = min(t_abs, T_SEQ - 1);
  const bool hiz = (t_abs >= T_SEQ - 1);
  short8 aq[4];
#pragma unroll
  for (int kc = 0; kc < 4; kc++) {
    short8 v = *(const short8*)(qplane + (size_t)tload * 64 + kc * 32 + quad * 8);
    if (kc >= 2 && hiz) v = (short8){0, 0, 0, 0, 0, 0, 0, 0};
    aq[kc] = v;
  }

  floatx4 o[4];
  float l_lane = 0.f;
#pragma unroll
  for (int i = 0; i < 4; i++) o[i] = (floatx4){0.f, 0.f, 0.f, 0.f};

  const int tstrip = tq0 + wave * 16;
  __hip_bfloat16* psw = &Ps[wave][0];

#define STAGE_TILE(JJ, BUF)                                                        \
  {                                                                                \
    const int s0_ = (JJ) * 64;                                                     \
    _Pragma("unroll") for (int ii = 0; ii < 2; ii++) {                             \
      const int i_ = wave * 2 + ii;                                                \
      const int r_ = i_ * 4 + (lane >> 4);                                         \
      const int sl_ = lane & 15;                                                   \
      const int g_ = (sl_ & 8) | ((sl_ ^ (r_ & 7)) & 7);                           \
      const int s_ = min(s0_ + r_, T_SEQ - 1);                                     \
      const short* src_ = (g_ < 8) ? (kplane + (size_t)s_ * 64 + g_ * 8)           \
                                   : (eplane + (size_t)s_ * 64 + (g_ - 8) * 8);    \
      load_lds16(src_, (char*)&Ks[BUF][0] + i_ * 1024);                            \
    }                                                                              \
    {                                                                              \
      const int d_ = wave * 8 + (lane >> 3);                                       \
      const int sl_ = lane & 7;                                                    \
      const int g_ = sl_ ^ (d_ & 7);                                               \
      load_lds16(vplane + (size_t)d_ * VT_STRIDE + s0_ + g_ * 8,                   \
                 (char*)&Vs[BUF][0] + wave * 1024);                                \
    }                                                                              \
  }

  STAGE_TILE(j0, 0)
  int buf = 0;

  for (int j = j0; j <= j1; ++j, buf ^= 1) {
    __syncthreads();
    if (j < j1) STAGE_TILE(j + 1, buf ^ 1)

    const int s0 = j * 64;
    if (s0 > tstrip + 15) continue;  // fully-masked strip

    const __hip_bfloat16* ks = &Ks[buf][0];
    const __hip_bfloat16* vs = &Vs[buf][0];

    // ---- S^T: lane gets S[t=col][s = st*16+quad*4+r]
    floatx4 sacc[4];
#pragma unroll
    for (int st = 0; st < 4; st++) {
      floatx4 c = {0.f, 0.f, 0.f, 0.f};
      const int row = st * 16 + col;
#pragma unroll
      for (int kc = 0; kc < 4; kc++) {
        const int ch = kc * 4 + quad;
        const int slot = (ch & 8) | ((ch ^ (row & 7)) & 7);
        short8 ka = *(const short8*)(ks + row * 128 + slot * 8);
        c = __builtin_amdgcn_mfma_f32_16x16x32_bf16(ka, aq[kc], c, 0, 0, 0);
      }
      sacc[st] = c;
    }

    // ---- causal mask (diagonal-straddling tiles only)
    if (s0 + 63 > tstrip) {
#pragma unroll
      for (int st = 0; st < 4; st++) {
        const int sbase = s0 + st * 16 + quad * 4;
#pragma unroll
        for (int r = 0; r < 4; r++)
          if (sbase + r > t_abs) sacc[st][r] = -INFINITY;
      }
    }

    // ---- no-max softmax numerator: P = exp(S/8); accumulate l per-lane
    float rs = 0.f;
#pragma unroll
    for (int st = 0; st < 4; st++)
#pragma unroll
      for (int r = 0; r < 4; r++) {
        const float p = __expf(sacc[st][r] * 0.125f);
        sacc[st][r] = p;
        rs += p;
      }
    l_lane += rs;

    // ---- P -> per-wave frag-major LDS (wave-private: no barrier)
#pragma unroll
    for (int st = 0; st < 4; st++) {
      __hip_bfloat16 pb[4];
#pragma unroll
      for (int r = 0; r < 4; r++) pb[r] = __float2bfloat16(sacc[st][r]);
      const int kcA = st >> 1;
      const int quadA = (st & 1) * 2 + (quad >> 1);
      const int off = ((kcA * 4 + quadA) * 16 + col) * 8 + (quad & 1) * 4;
      *(short4v*)(psw + off) = *(const short4v*)pb;
    }
    short8 pa[2];
#pragma unroll
    for (int kc = 0; kc < 2; kc++)
      pa[kc] = *(const short8*)(psw + ((kc * 4 + quad) * 16 + col) * 8);

    // ---- PV (no rescale needed)
#pragma unroll
    for (int nt = 0; nt < 4; nt++) {
      const int row = nt * 16 + col;
#pragma unroll
      for (int kc = 0; kc < 2; kc++) {
        const int slot = (kc * 4 + quad) ^ (row & 7);
        short8 vb = *(const short8*)(vs + row * 64 + slot * 8);
        o[nt] = __builtin_amdgcn_mfma_f32_16x16x32_bf16(pa[kc], vb, o[nt], 0, 0, 0);
      }
    }
  }

  // ---- epilogue
  l_lane += __shfl_xor(l_lane, 16, 64);
  l_lane += __shfl_xor(l_lane, 32, 64);  // full (or half-range) sum for t=tstrip+col

  if (b < 8) {
    // complete sum: write normalized ctx directly (all t < 1024, in-bounds)
    const float linv = 1.0f / l_lane;
    float linv_r[4];
#pragma unroll
    for (int r = 0; r < 4; r++) linv_r[r] = __shfl(linv, quad * 4 + r, 64);
#pragma unroll
    for (int r = 0; r < 4; r++) {
      const int t = tstrip + quad * 4 + r;
#pragma unroll
      for (int nt = 0; nt < 4; nt++)
        ctx[(size_t)t * D_MODEL + h * 64 + nt * 16 + col] =
            __float2bfloat16(o[nt][r] * linv_r[r]);
    }
  } else {
    // partial: store l and unnormalized O into split buffers (rows t-1024)
    if (lane < 16) {
      const int t = tstrip + lane;
      if (t < T_SEQ) {
        if (!alt)
          l0g[h * T1_ROWS + (t - 1024)] = l_lane;
        else
          l1g[h * T1_ROWS + (t - 1024)] = l_lane;
      }
    }
#pragma unroll
    for (int r = 0; r < 4; r++) {
      const int t = tstrip + quad * 4 + r;
      if (t < T_SEQ) {
        __hip_bfloat16* dst = (!alt ? O0 : O1) + (size_t)(t - 1024) * D_MODEL;
#pragma unroll
        for (int nt = 0; nt < 4; nt++)
          dst[h * 64 + nt * 16 + col] = __float2bfloat16(o[nt][r]);
      }
    }
  }
}

// ---------------------------------------------------------------------------
// finalize (t >= 1024 only): ctx[t] = (O0[t-1024]+O1[t-1024]) / (l0+l1)
// ---------------------------------------------------------------------------
__global__ __launch_bounds__(256) void finalize(
    const __hip_bfloat16* __restrict__ O0, const __hip_bfloat16* __restrict__ O1,
    const float* __restrict__ l0g, const float* __restrict__ l1g,
    __hip_bfloat16* __restrict__ ctx) {
  const int idx = blockIdx.x * 256 + threadIdx.x;  // chunk index (8 elems)
  const int tr = idx >> 7;                         // row - 1024
  const int t = 1024 + tr;
  if (t >= T_SEQ) return;
  const int ch = idx & 127;
  const int h = ch >> 3;  // 8 chunks per 64-elem head

  const float l = l0g[h * T1_ROWS + tr] + l1g[h * T1_ROWS + tr];
  const __hip_bfloat16* a = O0 + (size_t)tr * D_MODEL + ch * 8;
  const __hip_bfloat16* bsrc = O1 + (size_t)tr * D_MODEL + ch * 8;
  const float inv = 1.0f / l;
  __hip_bfloat16 outv[8];
#pragma unroll
  for (int i = 0; i < 8; i++)
    outv[i] = __float2bfloat16((bf2f(a[i]) + bf2f(bsrc[i])) * inv);
  *(short8*)(ctx + (size_t)t * D_MODEL + ch * 8) = *(const short8*)outv;
}

// ---------------------------------------------------------------------------
extern "C" void kernel_launch(void* const* d_in, const int* in_sizes, int n_in,
                              void* d_out, int out_size, void* d_ws, size_t ws_size,
                              hipStream_t stream) {
  const float* q = (const float*)d_in[0];
  const float* k = (const float*)d_in[1];
  const float* v = (const float*)d_in[2];
  const float* Wq_w = (const float*)d_in[4];
  const float* Wq_b = (const float*)d_in[5];
  const float* Wk_w = (const float*)d_in[6];
  const float* Wk_b = (const float*)d_in[7];
  const float* Wv_w = (const float*)d_in[8];
  const float* Wv_b = (const float*)d_in[9];
  const float* Er = (const float*)d_in[10];
  const float* Wo_w = (const float*)d_in[11];
  const float* Wo_b = (const float*)d_in[12];
  float* out = (float*)d_out;

  // ---- workspace carve-up (33.57 MB peak, proven budget)
  char* ws = (char*)d_ws;
  const size_t sz_plane = (size_t)T_SEQ * D_MODEL * 2;  // 4,196,352 B
  const size_t sz_w = (size_t)D_MODEL * D_MODEL * 2;    // 2,097,152 B
  __hip_bfloat16* qbf = (__hip_bfloat16*)ws;                   // dead after QKV GEMM
  __hip_bfloat16* kbf = (__hip_bfloat16*)(ws + sz_plane);      // dead after QKV GEMM
  __hip_bfloat16* vbf = (__hip_bfloat16*)(ws + 2 * sz_plane);  // dead after QKV GEMM
  char* wbase = ws + 3 * sz_plane;
  __hip_bfloat16* wob = (__hip_bfloat16*)(wbase);           // live till out-proj
  __hip_bfloat16* wqb = (__hip_bfloat16*)(wbase + sz_w);    // dead after QKV GEMM
  __hip_bfloat16* wkb = (__hip_bfloat16*)(wbase + 2 * sz_w);
  __hip_bfloat16* wvb = (__hip_bfloat16*)(wbase + 3 * sz_w);
  char* pbase = wbase + 4 * sz_w;
  __hip_bfloat16* qpr = (__hip_bfloat16*)(pbase);                // head-major
  __hip_bfloat16* kpr = (__hip_bfloat16*)(pbase + sz_plane);     // head-major
  __hip_bfloat16* vpr = (__hip_bfloat16*)(pbase + 2 * sz_plane); // row-major

  // overlays on dead front region (12.59 MB), written only after QKV GEMM:
  const size_t sz_vt = (size_t)N_HEAD * HEAD_DIM * VT_STRIDE * 2;  // 4,325,376
  const size_t sz_er = (size_t)T_SEQ * HEAD_DIM * 2;               // 262,272
  const size_t sz_Op = (size_t)T1_ROWS * D_MODEL * 2;              // 2,359,296
  const size_t sz_l = (size_t)N_HEAD * T1_ROWS * 4;                // 73,728
  __hip_bfloat16* vt = (__hip_bfloat16*)ws;
  __hip_bfloat16* er_bf = (__hip_bfloat16*)(ws + sz_vt);
  __hip_bfloat16* O0 = (__hip_bfloat16*)(ws + sz_vt + sz_er);
  __hip_bfloat16* O1 = (__hip_bfloat16*)(ws + sz_vt + sz_er + sz_Op);
  float* l0g = (float*)(ws + sz_vt + sz_er + 2 * sz_Op);
  float* l1g = (float*)(ws + sz_vt + sz_er + 2 * sz_Op + sz_l);
  // ctxb overlays dead wqb/wkb (+2KB of dead wvb), all dead post-QKV-GEMM
  __hip_bfloat16* ctxb = (__hip_bfloat16*)(wbase + sz_w);

  const dim3 blk(256);

  // 1) all fp32->bf16 casts in one launch
  cast_all<<<dim3(1025, 7), blk, 0, stream>>>(q, k, v, Wq_w, Wk_w, Wv_w, Wo_w, qbf,
                                              kbf, vbf, wqb, wkb, wvb, wob);

  // 2) fused QKV projections: Q,K head-major bf16; V row-major bf16
  //    BM=64 -> grid (8, 33, 3) = 792 blocks (~3/CU), double-buffered K-loop
  mfma_gemm<128, 2><<<dim3(8, 33, 3), blk, 0, stream>>>(
      qbf, kbf, vbf, wqb, wkb, wvb, Wq_b, Wk_b, Wv_b, qpr, kpr, vpr, T_SEQ);

  // 3) V transpose + Er cast (one launch)
  transpose_v_er<<<dim3(65, 17), blk, 0, stream>>>(vpr, vt, Er, er_bf);

  // 4) flash attention (direct ctx for t<1024; split partials for t>=1024)
  flash_attn<<<dim3(26, N_HEAD), dim3(512), 0, stream>>>(qpr, kpr, er_bf, vt, ctxb,
                                                         O0, O1, l0g, l1g);

  // 5) merge split halves for t>=1024
  finalize<<<dim3((1025 * 128 + 255) / 256), blk, 0, stream>>>(O0, O1, l0g, l1g, ctxb);

  // 6) output projection (fp32 out), 64x64 tiles -> 528 blocks (~2/CU)
  mfma_gemm<64, 0><<<dim3(16, 33, 1), blk, 0, stream>>>(
      ctxb, ctxb, ctxb, wob, wob, wob, Wo_b, Wo_b, Wo_b, out, out, out, T_SEQ);
}

// Round 9
// 208.371 us; speedup vs baseline: 1.0009x; 1.0009x over previous
//
#include <hip/hip_runtime.h>
#include <hip/hip_bf16.h>
#include <math.h>

constexpr int T_SEQ = 2049;
constexpr int D_MODEL = 1024;
constexpr int N_HEAD = 16;
constexpr int HEAD_DIM = 64;
constexpr int VT_STRIDE = 2112;  // 2048+64: flash V-tile reads stay in-bounds
constexpr int T1_ROWS = 1152;    // rows 1024..2175 for split partial buffers

typedef __attribute__((ext_vector_type(8))) short short8;
typedef __attribute__((ext_vector_type(4))) short short4v;
typedef __attribute__((ext_vector_type(4))) float floatx4;

// async global->LDS, 16B per lane; LDS dest = wave-uniform base + lane*16
__device__ inline void load_lds16(const void* g, void* l) {
  __builtin_amdgcn_global_load_lds(
      (const __attribute__((address_space(1))) unsigned int*)g,
      (__attribute__((address_space(3))) unsigned int*)l, 16, 0, 0);
}

__device__ inline short8 cvt8_bf16(const float* p) {
  float4 a = *(const float4*)p, b = *(const float4*)(p + 4);
  __hip_bfloat16 t[8] = {__float2bfloat16(a.x), __float2bfloat16(a.y),
                         __float2bfloat16(a.z), __float2bfloat16(a.w),
                         __float2bfloat16(b.x), __float2bfloat16(b.y),
                         __float2bfloat16(b.z), __float2bfloat16(b.w)};
  return *(const short8*)t;
}

__device__ inline float bf2f(__hip_bfloat16 x) { return __bfloat162float(x); }

// ---------------------------------------------------------------------------
// Mega-cast: all 8 fp32->bf16 tensors in one launch. grid=(1025,8)
// z: 0..2 -> q,k,v; 3..6 -> Wq,Wk,Wv,Wo; 7 -> Er
// ---------------------------------------------------------------------------
__global__ __launch_bounds__(256) void cast_all(
    const float* __restrict__ q, const float* __restrict__ k,
    const float* __restrict__ v, const float* __restrict__ wq,
    const float* __restrict__ wk, const float* __restrict__ wv,
    const float* __restrict__ wo, const float* __restrict__ er,
    __hip_bfloat16* __restrict__ qo, __hip_bfloat16* __restrict__ ko,
    __hip_bfloat16* __restrict__ vo, __hip_bfloat16* __restrict__ wqo,
    __hip_bfloat16* __restrict__ wko, __hip_bfloat16* __restrict__ wvo,
    __hip_bfloat16* __restrict__ woo, __hip_bfloat16* __restrict__ ero) {
  const int z = blockIdx.y;
  const float* in;
  __hip_bfloat16* out;
  int n;
  switch (z) {
    case 0: in = q; out = qo; n = T_SEQ * D_MODEL; break;
    case 1: in = k; out = ko; n = T_SEQ * D_MODEL; break;
    case 2: in = v; out = vo; n = T_SEQ * D_MODEL; break;
    case 3: in = wq; out = wqo; n = D_MODEL * D_MODEL; break;
    case 4: in = wk; out = wko; n = D_MODEL * D_MODEL; break;
    case 5: in = wv; out = wvo; n = D_MODEL * D_MODEL; break;
    case 6: in = wo; out = woo; n = D_MODEL * D_MODEL; break;
    default: in = er; out = ero; n = T_SEQ * HEAD_DIM; break;
  }
  const int i = (blockIdx.x * 256 + threadIdx.x) * 8;
  if (i + 8 > n) return;
  *(short8*)(out + i) = cvt8_bf16(in + i);
}

// ---------------------------------------------------------------------------
// bf16 MFMA GEMM: C[M x 1024] = A[M x 1024] @ W[1024 x 1024]^T + bias
// BM x BN tile, BK=64, 256 threads (2x2 waves; wave tile BM/2 x BN/2).
// Double-buffered LDS, one barrier per K-iter. Conflict-free XOR staging
// (chunk c of row r at slot c^(r&7); SQ_LDS_BANK_CONFLICT=0 measured r7/r8).
// OUTK 0: fp32 row-major out.
// OUTK 2: QKV mode -- z<2: bf16 head-major [h][t][hd]; z==2: bf16 V^T
//         [h][d][t] (stride VT_STRIDE) written directly (replaces transpose
//         kernel; t-pad left unwritten -- flash multiplies it by P=0).
// ---------------------------------------------------------------------------
template <int BM, int BN, int OUTK>
__global__ __launch_bounds__(256) void mfma_gemm(
    const __hip_bfloat16* __restrict__ A0, const __hip_bfloat16* __restrict__ A1,
    const __hip_bfloat16* __restrict__ A2, const __hip_bfloat16* __restrict__ W0,
    const __hip_bfloat16* __restrict__ W1, const __hip_bfloat16* __restrict__ W2,
    const float* __restrict__ bias0, const float* __restrict__ bias1,
    const float* __restrict__ bias2, void* C0, void* C1, void* C2, int M) {
  constexpr int K = D_MODEL;
  constexpr int MT = BM / 32;  // A fragment tiles per wave
  constexpr int NT = BN / 32;  // B fragment tiles per wave
  __shared__ __align__(16) __hip_bfloat16 As[2][BM * 64];
  __shared__ __align__(16) __hip_bfloat16 Bs[2][BN * 64];

  const int z = blockIdx.z;
  const short* A = (const short*)(z == 0 ? A0 : z == 1 ? A1 : A2);
  const short* W = (const short*)(z == 0 ? W0 : z == 1 ? W1 : W2);
  const float* bias = z == 0 ? bias0 : z == 1 ? bias1 : bias2;
  void* C = z == 0 ? C0 : z == 1 ? C1 : C2;

  const int tid = threadIdx.x;
  const int wave = tid >> 6, lane = tid & 63;
  const int col = lane & 15, quad = lane >> 4;
  const int wm = wave >> 1, wn = wave & 1;
  const int m0 = blockIdx.y * BM, n0 = blockIdx.x * BN;

  // staging lane geometry: 8 rows x 8 slots (16B) per instruction
  const int srow = lane >> 3;    // 0..7
  const int sslot = lane & 7;    // 0..7
  const int sch = sslot ^ srow;  // global chunk fetched into this lane's slot

  floatx4 acc[MT][NT];
#pragma unroll
  for (int i = 0; i < MT; i++)
#pragma unroll
    for (int j = 0; j < NT; j++) acc[i][j] = (floatx4){0.f, 0.f, 0.f, 0.f};

#define GSTAGE(K0, BUF)                                                     \
  {                                                                         \
    _Pragma("unroll") for (int ii = 0; ii < BM / 32; ii++) {                \
      const int rb = (wave * (BM / 32) + ii) * 8;                           \
      const int am = min(m0 + rb + srow, M - 1);                            \
      load_lds16(A + (size_t)am * K + (K0) + sch * 8,                       \
                 (char*)&As[BUF][0] + rb * 128);                            \
    }                                                                       \
    _Pragma("unroll") for (int ii = 0; ii < BN / 32; ii++) {                \
      const int rb = (wave * (BN / 32) + ii) * 8;                           \
      const int bn = n0 + rb + srow;                                        \
      load_lds16(W + (size_t)bn * K + (K0) + sch * 8,                       \
                 (char*)&Bs[BUF][0] + rb * 128);                            \
    }                                                                       \
  }

  GSTAGE(0, 0)
  int buf = 0;

  for (int kb = 0; kb < K / 64; ++kb, buf ^= 1) {
    __syncthreads();  // drain stage(kb); all waves done reading buf^1
    if (kb + 1 < K / 64) GSTAGE((kb + 1) * 64, buf ^ 1)

    const __hip_bfloat16* as = &As[buf][0];
    const __hip_bfloat16* bs = &Bs[buf][0];
#pragma unroll
    for (int kk = 0; kk < 2; kk++) {
      short8 af[MT], bf[NT];
#pragma unroll
      for (int t = 0; t < MT; t++) {
        const int ra = wm * (BM / 2) + t * 16 + col;
        af[t] = *(const short8*)(as + ra * 64 + ((kk * 4 + quad) ^ (ra & 7)) * 8);
      }
#pragma unroll
      for (int t = 0; t < NT; t++) {
        const int rb = wn * (BN / 2) + t * 16 + col;
        bf[t] = *(const short8*)(bs + rb * 64 + ((kk * 4 + quad) ^ (rb & 7)) * 8);
      }
#pragma unroll
      for (int mt = 0; mt < MT; mt++)
#pragma unroll
        for (int nt = 0; nt < NT; nt++)
          acc[mt][nt] = __builtin_amdgcn_mfma_f32_16x16x32_bf16(af[mt], bf[nt],
                                                                acc[mt][nt], 0, 0, 0);
    }
  }

#pragma unroll
  for (int mt = 0; mt < MT; mt++) {
    const int mb = m0 + wm * (BM / 2) + mt * 16 + quad * 4;
#pragma unroll
    for (int nt = 0; nt < NT; nt++) {
      const int n = n0 + wn * (BN / 2) + nt * 16 + col;
      if (OUTK == 2 && z == 2) {
        // V^T direct write: vt[n][t] for t=mb..mb+3, packed 8B store
        __hip_bfloat16 pb[4];
#pragma unroll
        for (int r = 0; r < 4; r++)
          pb[r] = __float2bfloat16(acc[mt][nt][r] + bias[n]);
        __hip_bfloat16* vrow = (__hip_bfloat16*)C + (size_t)n * VT_STRIDE;
        if (mb + 4 <= M) {
          *(short4v*)(vrow + mb) = *(const short4v*)pb;
        } else {
#pragma unroll
          for (int r = 0; r < 4; r++)
            if (mb + r < M) vrow[mb + r] = pb[r];
        }
      } else {
#pragma unroll
        for (int r = 0; r < 4; r++) {
          const int m = mb + r;
          if (m >= M) continue;
          const float val = acc[mt][nt][r] + bias[n];
          if (OUTK == 0) {
            ((float*)C)[(size_t)m * D_MODEL + n] = val;
          } else {  // head-major [h][t][hd] for Q,K
            const int h = n >> 6, hd = n & 63;
            ((__hip_bfloat16*)C)[((size_t)h * T_SEQ + m) * HEAD_DIM + hd] =
                __float2bfloat16(val);
          }
        }
      }
    }
  }
}

// ---------------------------------------------------------------------------
// Flash attention v3: S^T trick + no-max softmax (logits bounded ~|4.5| ->
// exp <= ~90, fp32-safe) -> order-free s-tiles -> split-s load balancing.
// b<8: qt=b, full s-range, COMPLETE sum -> write normalized ctx directly.
// b>=8: qt=8+((b-8)>>1), s-half (b-8)&1 -> partial (O,l) buffers (t>=1024).
// ---------------------------------------------------------------------------
__global__ __launch_bounds__(512, 4) void flash_attn(
    const __hip_bfloat16* __restrict__ qh, const __hip_bfloat16* __restrict__ kh,
    const __hip_bfloat16* __restrict__ er, const __hip_bfloat16* __restrict__ vt,
    __hip_bfloat16* __restrict__ ctx, __hip_bfloat16* __restrict__ O0,
    __hip_bfloat16* __restrict__ O1, float* __restrict__ l0g,
    float* __restrict__ l1g) {
  __shared__ __align__(16) __hip_bfloat16 Ks[2][64 * 128];  // [s][kaug] swizzled
  __shared__ __align__(16) __hip_bfloat16 Vs[2][64 * 64];   // [d][s] swizzled
  __shared__ __align__(16) __hip_bfloat16 Ps[8][1024];      // per-wave frag-major

  const int tid = threadIdx.x;
  const int h = blockIdx.y;
  const int b = blockIdx.x;  // 0..25

  const int qt = (b < 8) ? b : 8 + ((b - 8) >> 1);
  const int tq0 = qt * 128;
  const int jmax = min(tq0 + 127, T_SEQ - 1) >> 6;
  int j0, j1;
  bool alt;
  if (b < 8) {
    j0 = 0; j1 = jmax; alt = false;
  } else {
    const int mid = (jmax + 1) >> 1;
    alt = (b - 8) & 1;
    j0 = alt ? mid : 0;
    j1 = alt ? jmax : mid - 1;
  }

  const int wave = tid >> 6;
  const int lane = tid & 63;
  const int col = lane & 15;
  const int quad = lane >> 4;

  const short* qplane = (const short*)(qh + (size_t)h * T_SEQ * HEAD_DIM);
  const short* kplane = (const short*)(kh + (size_t)h * T_SEQ * HEAD_DIM);
  const short* eplane = (const short*)er;
  const short* vplane = (const short*)(vt + (size_t)h * HEAD_DIM * VT_STRIDE);

  // ---- Q fragments (B-operand): lane holds Qaug[t = tq0+wave*16+col][k]
  const int t_abs = tq0 + wave * 16 + col;
  const int tload = min(t_abs, T_SEQ - 1);
  const bool hiz = (t_abs >= T_SEQ - 1);
  short8 aq[4];
#pragma unroll
  for (int kc = 0; kc < 4; kc++) {
    short8 v = *(const short8*)(qplane + (size_t)tload * 64 + kc * 32 + quad * 8);
    if (kc >= 2 && hiz) v = (short8){0, 0, 0, 0, 0, 0, 0, 0};
    aq[kc] = v;
  }

  floatx4 o[4];
  float l_lane = 0.f;
#pragma unroll
  for (int i = 0; i < 4; i++) o[i] = (floatx4){0.f, 0.f, 0.f, 0.f};

  const int tstrip = tq0 + wave * 16;
  __hip_bfloat16* psw = &Ps[wave][0];

#define STAGE_TILE(JJ, BUF)                                                        \
  {                                                                                \
    const int s0_ = (JJ) * 64;                                                     \
    _Pragma("unroll") for (int ii = 0; ii < 2; ii++) {                             \
      const int i_ = wave * 2 + ii;                                                \
      const int r_ = i_ * 4 + (lane >> 4);                                         \
      const int sl_ = lane & 15;                                                   \
      const int g_ = (sl_ & 8) | ((sl_ ^ (r_ & 7)) & 7);                           \
      const int s_ = min(s0_ + r_, T_SEQ - 1);                                     \
      const short* src_ = (g_ < 8) ? (kplane + (size_t)s_ * 64 + g_ * 8)           \
                                   : (eplane + (size_t)s_ * 64 + (g_ - 8) * 8);    \
      load_lds16(src_, (char*)&Ks[BUF][0] + i_ * 1024);                            \
    }                                                                              \
    {                                                                              \
      const int d_ = wave * 8 + (lane >> 3);                                       \
      const int sl_ = lane & 7;                                                    \
      const int g_ = sl_ ^ (d_ & 7);                                               \
      load_lds16(vplane + (size_t)d_ * VT_STRIDE + s0_ + g_ * 8,                   \
                 (char*)&Vs[BUF][0] + wave * 1024);                                \
    }                                                                              \
  }

  STAGE_TILE(j0, 0)
  int buf = 0;

  for (int j = j0; j <= j1; ++j, buf ^= 1) {
    __syncthreads();
    if (j < j1) STAGE_TILE(j + 1, buf ^ 1)

    const int s0 = j * 64;
    if (s0 > tstrip + 15) continue;  // fully-masked strip

    const __hip_bfloat16* ks = &Ks[buf][0];
    const __hip_bfloat16* vs = &Vs[buf][0];

    // ---- S^T: lane gets S[t=col][s = st*16+quad*4+r]
    floatx4 sacc[4];
#pragma unroll
    for (int st = 0; st < 4; st++) {
      floatx4 c = {0.f, 0.f, 0.f, 0.f};
      const int row = st * 16 + col;
#pragma unroll
      for (int kc = 0; kc < 4; kc++) {
        const int ch = kc * 4 + quad;
        const int slot = (ch & 8) | ((ch ^ (row & 7)) & 7);
        short8 ka = *(const short8*)(ks + row * 128 + slot * 8);
        c = __builtin_amdgcn_mfma_f32_16x16x32_bf16(ka, aq[kc], c, 0, 0, 0);
      }
      sacc[st] = c;
    }

    // ---- causal mask (diagonal-straddling tiles only)
    if (s0 + 63 > tstrip) {
#pragma unroll
      for (int st = 0; st < 4; st++) {
        const int sbase = s0 + st * 16 + quad * 4;
#pragma unroll
        for (int r = 0; r < 4; r++)
          if (sbase + r > t_abs) sacc[st][r] = -INFINITY;
      }
    }

    // ---- no-max softmax numerator: P = exp(S/8); accumulate l per-lane
    float rs = 0.f;
#pragma unroll
    for (int st = 0; st < 4; st++)
#pragma unroll
      for (int r = 0; r < 4; r++) {
        const float p = __expf(sacc[st][r] * 0.125f);
        sacc[st][r] = p;
        rs += p;
      }
    l_lane += rs;

    // ---- P -> per-wave frag-major LDS (wave-private: no barrier)
#pragma unroll
    for (int st = 0; st < 4; st++) {
      __hip_bfloat16 pb[4];
#pragma unroll
      for (int r = 0; r < 4; r++) pb[r] = __float2bfloat16(sacc[st][r]);
      const int kcA = st >> 1;
      const int quadA = (st & 1) * 2 + (quad >> 1);
      const int off = ((kcA * 4 + quadA) * 16 + col) * 8 + (quad & 1) * 4;
      *(short4v*)(psw + off) = *(const short4v*)pb;
    }
    short8 pa[2];
#pragma unroll
    for (int kc = 0; kc < 2; kc++)
      pa[kc] = *(const short8*)(psw + ((kc * 4 + quad) * 16 + col) * 8);

    // ---- PV (no rescale needed)
#pragma unroll
    for (int nt = 0; nt < 4; nt++) {
      const int row = nt * 16 + col;
#pragma unroll
      for (int kc = 0; kc < 2; kc++) {
        const int slot = (kc * 4 + quad) ^ (row & 7);
        short8 vb = *(const short8*)(vs + row * 64 + slot * 8);
        o[nt] = __builtin_amdgcn_mfma_f32_16x16x32_bf16(pa[kc], vb, o[nt], 0, 0, 0);
      }
    }
  }

  // ---- epilogue
  l_lane += __shfl_xor(l_lane, 16, 64);
  l_lane += __shfl_xor(l_lane, 32, 64);  // full (or half-range) sum for t=tstrip+col

  if (b < 8) {
    // complete sum: write normalized ctx directly (all t < 1024, in-bounds)
    const float linv = 1.0f / l_lane;
    float linv_r[4];
#pragma unroll
    for (int r = 0; r < 4; r++) linv_r[r] = __shfl(linv, quad * 4 + r, 64);
#pragma unroll
    for (int r = 0; r < 4; r++) {
      const int t = tstrip + quad * 4 + r;
#pragma unroll
      for (int nt = 0; nt < 4; nt++)
        ctx[(size_t)t * D_MODEL + h * 64 + nt * 16 + col] =
            __float2bfloat16(o[nt][r] * linv_r[r]);
    }
  } else {
    // partial: store l and unnormalized O into split buffers (rows t-1024)
    if (lane < 16) {
      const int t = tstrip + lane;
      if (t < T_SEQ) {
        if (!alt)
          l0g[h * T1_ROWS + (t - 1024)] = l_lane;
        else
          l1g[h * T1_ROWS + (t - 1024)] = l_lane;
      }
    }
#pragma unroll
    for (int r = 0; r < 4; r++) {
      const int t = tstrip + quad * 4 + r;
      if (t < T_SEQ) {
        __hip_bfloat16* dst = (!alt ? O0 : O1) + (size_t)(t - 1024) * D_MODEL;
#pragma unroll
        for (int nt = 0; nt < 4; nt++)
          dst[h * 64 + nt * 16 + col] = __float2bfloat16(o[nt][r]);
      }
    }
  }
}

// ---------------------------------------------------------------------------
// finalize (t >= 1024 only): ctx[t] = (O0[t-1024]+O1[t-1024]) / (l0+l1)
// ---------------------------------------------------------------------------
__global__ __launch_bounds__(256) void finalize(
    const __hip_bfloat16* __restrict__ O0, const __hip_bfloat16* __restrict__ O1,
    const float* __restrict__ l0g, const float* __restrict__ l1g,
    __hip_bfloat16* __restrict__ ctx) {
  const int idx = blockIdx.x * 256 + threadIdx.x;  // chunk index (8 elems)
  const int tr = idx >> 7;                         // row - 1024
  const int t = 1024 + tr;
  if (t >= T_SEQ) return;
  const int ch = idx & 127;
  const int h = ch >> 3;  // 8 chunks per 64-elem head

  const float l = l0g[h * T1_ROWS + tr] + l1g[h * T1_ROWS + tr];
  const __hip_bfloat16* a = O0 + (size_t)tr * D_MODEL + ch * 8;
  const __hip_bfloat16* bsrc = O1 + (size_t)tr * D_MODEL + ch * 8;
  const float inv = 1.0f / l;
  __hip_bfloat16 outv[8];
#pragma unroll
  for (int i = 0; i < 8; i++)
    outv[i] = __float2bfloat16((bf2f(a[i]) + bf2f(bsrc[i])) * inv);
  *(short8*)(ctx + (size_t)t * D_MODEL + ch * 8) = *(const short8*)outv;
}

// ---------------------------------------------------------------------------
extern "C" void kernel_launch(void* const* d_in, const int* in_sizes, int n_in,
                              void* d_out, int out_size, void* d_ws, size_t ws_size,
                              hipStream_t stream) {
  const float* q = (const float*)d_in[0];
  const float* k = (const float*)d_in[1];
  const float* v = (const float*)d_in[2];
  const float* Wq_w = (const float*)d_in[4];
  const float* Wq_b = (const float*)d_in[5];
  const float* Wk_w = (const float*)d_in[6];
  const float* Wk_b = (const float*)d_in[7];
  const float* Wv_w = (const float*)d_in[8];
  const float* Wv_b = (const float*)d_in[9];
  const float* Er = (const float*)d_in[10];
  const float* Wo_w = (const float*)d_in[11];
  const float* Wo_b = (const float*)d_in[12];
  float* out = (float*)d_out;

  // ---- FLAT workspace layout (ws_size = 256 MiB measured from harness
  //      re-poison WRITE_SIZE; total use ~45 MB, no overlays/aliasing)
  char* p = (char*)d_ws;
  auto carve = [&](size_t bytes) {
    char* r = p;
    p += (bytes + 255) & ~(size_t)255;  // 256B-align each region
    return r;
  };
  const size_t sz_plane = (size_t)T_SEQ * D_MODEL * 2;  // 4,196,352 B
  const size_t sz_w = (size_t)D_MODEL * D_MODEL * 2;    // 2,097,152 B
  __hip_bfloat16* qbf = (__hip_bfloat16*)carve(sz_plane);
  __hip_bfloat16* kbf = (__hip_bfloat16*)carve(sz_plane);
  __hip_bfloat16* vbf = (__hip_bfloat16*)carve(sz_plane);
  __hip_bfloat16* wqb = (__hip_bfloat16*)carve(sz_w);
  __hip_bfloat16* wkb = (__hip_bfloat16*)carve(sz_w);
  __hip_bfloat16* wvb = (__hip_bfloat16*)carve(sz_w);
  __hip_bfloat16* wob = (__hip_bfloat16*)carve(sz_w);
  __hip_bfloat16* qpr = (__hip_bfloat16*)carve(sz_plane);  // head-major
  __hip_bfloat16* kpr = (__hip_bfloat16*)carve(sz_plane);  // head-major
  __hip_bfloat16* vt =
      (__hip_bfloat16*)carve((size_t)N_HEAD * HEAD_DIM * VT_STRIDE * 2);
  __hip_bfloat16* er_bf = (__hip_bfloat16*)carve((size_t)T_SEQ * HEAD_DIM * 2);
  __hip_bfloat16* O0 = (__hip_bfloat16*)carve((size_t)T1_ROWS * D_MODEL * 2);
  __hip_bfloat16* O1 = (__hip_bfloat16*)carve((size_t)T1_ROWS * D_MODEL * 2);
  float* l0g = (float*)carve((size_t)N_HEAD * T1_ROWS * 4);
  float* l1g = (float*)carve((size_t)N_HEAD * T1_ROWS * 4);
  __hip_bfloat16* ctxb = (__hip_bfloat16*)carve(sz_plane);

  const dim3 blk(256);

  // 1) all fp32->bf16 casts (q,k,v,4 weights,Er) in one launch
  cast_all<<<dim3(1025, 8), blk, 0, stream>>>(q, k, v, Wq_w, Wk_w, Wv_w, Wo_w, Er,
                                              qbf, kbf, vbf, wqb, wkb, wvb, wob,
                                              er_bf);

  // 2) fused QKV projections: Q,K head-major; V written TRANSPOSED to vt
  //    BM=64,BN=128 -> grid (8,33,3)=792 blocks, double-buffered K-loop
  mfma_gemm<64, 128, 2><<<dim3(8, 33, 3), blk, 0, stream>>>(
      qbf, kbf, vbf, wqb, wkb, wvb, Wq_b, Wk_b, Wv_b, qpr, kpr, vt, T_SEQ);

  // 3) flash attention (direct ctx for t<1024; split partials for t>=1024)
  flash_attn<<<dim3(26, N_HEAD), dim3(512), 0, stream>>>(qpr, kpr, er_bf, vt, ctxb,
                                                         O0, O1, l0g, l1g);

  // 4) merge split halves for t>=1024
  finalize<<<dim3((1025 * 128 + 255) / 256), blk, 0, stream>>>(O0, O1, l0g, l1g, ctxb);

  // 5) output projection (fp32 out): BM=128,BN=64 -> 272 blocks, 48KB LDS
  mfma_gemm<128, 64, 0><<<dim3(16, 17, 1), blk, 0, stream>>>(
      ctxb, ctxb, ctxb, wob, wob, wob, Wo_b, Wo_b, Wo_b, out, out, out, T_SEQ);
}